// Round 1
// baseline (4887.640 us; speedup 1.0000x reference)
//
#include <hip/hip_runtime.h>
#include <cstdint>
#include <cstddef>

#define B_ 4096
#define L_ 12
#define A_ 768
#define F_ 4096
#define NTRI 78

#define BM 128
#define BN 128
#define BK 32

typedef __bf16 bf16x8 __attribute__((ext_vector_type(8)));
typedef float f32x4 __attribute__((ext_vector_type(4)));
typedef unsigned short u16x4 __attribute__((ext_vector_type(4)));

__device__ __forceinline__ unsigned short f32_to_bf16(float f) {
  unsigned int u = __float_as_uint(f);
  u += 0x7fffu + ((u >> 16) & 1u);   // round-to-nearest-even
  return (unsigned short)(u >> 16);
}

__device__ __forceinline__ void gload_lds16(const void* g, void* l) {
  __builtin_amdgcn_global_load_lds(
      (const __attribute__((address_space(1))) void*)g,
      (__attribute__((address_space(3))) void*)l,
      16, 0, 0);
}

// ---------------------------------------------------------------------------
// prep_sx: sx[l][b][a] = (x[b][l][a] - mean[l][a]) / std[l][a]  (bf16)
// ---------------------------------------------------------------------------
__global__ __launch_bounds__(256) void prep_sx(
    const float* __restrict__ x, const float* __restrict__ mean,
    const float* __restrict__ stdv, unsigned short* __restrict__ sx) {
  size_t i4 = (size_t)blockIdx.x * 256 + threadIdx.x;
  size_t e = i4 * 4;
  if (e >= (size_t)B_ * L_ * A_) return;
  unsigned int a = (unsigned int)(e % A_);
  unsigned int t = (unsigned int)(e / A_);
  unsigned int b = t / L_;
  unsigned int l = t % L_;
  float4 xv = *(const float4*)(x + e);
  float4 mv = *(const float4*)(mean + (size_t)l * A_ + a);
  float4 sv = *(const float4*)(stdv + (size_t)l * A_ + a);
  u16x4 o;
  o.x = f32_to_bf16((xv.x - mv.x) / sv.x);
  o.y = f32_to_bf16((xv.y - mv.y) / sv.y);
  o.z = f32_to_bf16((xv.z - mv.z) / sv.z);
  o.w = f32_to_bf16((xv.w - mv.w) / sv.w);
  *(u16x4*)(sx + ((size_t)l * B_ + b) * A_ + a) = o;
}

// ---------------------------------------------------------------------------
// transpose_cvt: per matrix z (R x C f32, row-major) -> out (C x R bf16)
// ---------------------------------------------------------------------------
__global__ __launch_bounds__(256) void transpose_cvt(
    const float* __restrict__ in, unsigned short* __restrict__ out,
    int R, int C) {
  __shared__ float tile[32][33];
  const float* inz = in + (size_t)blockIdx.z * R * C;
  unsigned short* outz = out + (size_t)blockIdx.z * R * C;
  int c0 = blockIdx.x * 32, r0 = blockIdx.y * 32;
  int tx = threadIdx.x, ty = threadIdx.y;
#pragma unroll
  for (int q = 0; q < 4; ++q) {
    int r = ty + q * 8;
    tile[r][tx] = inz[(size_t)(r0 + r) * C + (c0 + tx)];
  }
  __syncthreads();
#pragma unroll
  for (int q = 0; q < 4; ++q) {
    int r = ty + q * 8;
    outz[(size_t)(c0 + r) * R + (r0 + tx)] = f32_to_bf16(tile[tx][r]);
  }
}

// ---------------------------------------------------------------------------
// Encoder GEMM: enc[b,l,f] = sum_a sx[l,b,a] * WencT[l,f,a]
// Writes enc (f32, d_out layout B,L,F) and act (bf16, ws layout L,B,F).
// m97 structure: 128x128 tile, BK=32, 4 waves, global_load_lds width 16.
// ---------------------------------------------------------------------------
__global__ __launch_bounds__(256) void enc_gemm(
    const unsigned short* __restrict__ sxT,   // (L,B,A)
    const unsigned short* __restrict__ wT,    // (L,F,A)
    const float* __restrict__ theta,          // (L,F)
    float* __restrict__ enc_out,              // (B,L,F)
    unsigned short* __restrict__ act)         // (L,B,F)
{
  __shared__ unsigned short Asm[BM * BK];
  __shared__ unsigned short Bsm[BN * BK];

  const int l = blockIdx.z;
  const int m0 = blockIdx.x * BM;
  const int n0 = blockIdx.y * BN;
  const int tid = threadIdx.x;
  const int lane = tid & 63;
  const int wv = tid >> 6;
  const int wr = (wv >> 1) * 64;
  const int wc = (wv & 1) * 64;

  const unsigned short* Ag = sxT + ((size_t)l * B_ + m0) * A_;
  const unsigned short* Bg = wT + ((size_t)l * F_ + n0) * A_;

  f32x4 acc[4][4] = {};

  // staging geometry: off = q*4096 + wv*1024 + lane*16 bytes
  const int srow = wv * 16 + (lane >> 2);   // + q*64
  const int scol = (lane & 3) * 8;          // element col within BK

  for (int kt = 0; kt < A_ / BK; ++kt) {
    const int k0 = kt * BK;
#pragma unroll
    for (int q = 0; q < 2; ++q) {
      gload_lds16(Ag + (size_t)(srow + q * 64) * A_ + (k0 + scol),
                  (char*)Asm + q * 4096 + wv * 1024);
      gload_lds16(Bg + (size_t)(srow + q * 64) * A_ + (k0 + scol),
                  (char*)Bsm + q * 4096 + wv * 1024);
    }
    __syncthreads();
    const int ar = wr + (lane & 15);
    const int br = wc + (lane & 15);
    const int ak = (lane >> 4) * 8;
    bf16x8 af[4], bfr[4];
#pragma unroll
    for (int t = 0; t < 4; ++t) {
      af[t] = *(const bf16x8*)&Asm[(ar + t * 16) * BK + ak];
      bfr[t] = *(const bf16x8*)&Bsm[(br + t * 16) * BK + ak];
    }
#pragma unroll
    for (int mi = 0; mi < 4; ++mi)
#pragma unroll
      for (int ni = 0; ni < 4; ++ni)
        acc[mi][ni] = __builtin_amdgcn_mfma_f32_16x16x32_bf16(
            af[mi], bfr[ni], acc[mi][ni], 0, 0, 0);
    __syncthreads();
  }

  const int rb = (lane >> 4) * 4;
  const int cb = lane & 15;
#pragma unroll
  for (int ni = 0; ni < 4; ++ni) {
    const int gcol = n0 + wc + ni * 16 + cb;
    const float th = theta[(size_t)l * F_ + gcol];
#pragma unroll
    for (int mi = 0; mi < 4; ++mi) {
      const int growb = m0 + wr + mi * 16 + rb;
#pragma unroll
      for (int j = 0; j < 4; ++j) {
        const float v = acc[mi][ni][j];
        const size_t grow = (size_t)(growb + j);
        enc_out[(grow * L_ + l) * F_ + gcol] = v;
        act[((size_t)l * B_ + grow) * F_ + gcol] =
            (v > th) ? f32_to_bf16(v) : (unsigned short)0;
      }
    }
  }
}

// ---------------------------------------------------------------------------
// Decoder GEMM: logits[b,i,a] = sum_{l<=i} sum_f act[l,b,f] * WdecT[tri(i,l),a,f]
// ---------------------------------------------------------------------------
__global__ __launch_bounds__(256) void dec_gemm(
    const unsigned short* __restrict__ act,    // (L,B,F)
    const unsigned short* __restrict__ wdecT,  // (NTRI,A,F)
    float* __restrict__ logits)                // (B,L,A)
{
  __shared__ unsigned short Asm[BM * BK];
  __shared__ unsigned short Bsm[BN * BK];

  const int i = L_ - 1 - blockIdx.z;   // heavy layers first
  const int m0 = blockIdx.x * BM;
  const int n0 = blockIdx.y * BN;
  const int tid = threadIdx.x;
  const int lane = tid & 63;
  const int wv = tid >> 6;
  const int wr = (wv >> 1) * 64;
  const int wc = (wv & 1) * 64;

  const int triBase = i * (i + 1) / 2;
  const int KT = (i + 1) * (F_ / BK);

  f32x4 acc[4][4] = {};

  const int srow = wv * 16 + (lane >> 2);
  const int scol = (lane & 3) * 8;

  for (int kt = 0; kt < KT; ++kt) {
    const int l = kt >> 7;               // F_/BK = 128 tiles per layer
    const int kk0 = (kt & 127) * BK;
    const unsigned short* Ag = act + ((size_t)l * B_ + m0) * F_ + kk0;
    const unsigned short* Bg =
        wdecT + ((size_t)(triBase + l) * A_ + n0) * F_ + kk0;
#pragma unroll
    for (int q = 0; q < 2; ++q) {
      gload_lds16(Ag + (size_t)(srow + q * 64) * F_ + scol,
                  (char*)Asm + q * 4096 + wv * 1024);
      gload_lds16(Bg + (size_t)(srow + q * 64) * F_ + scol,
                  (char*)Bsm + q * 4096 + wv * 1024);
    }
    __syncthreads();
    const int ar = wr + (lane & 15);
    const int br = wc + (lane & 15);
    const int ak = (lane >> 4) * 8;
    bf16x8 af[4], bfr[4];
#pragma unroll
    for (int t = 0; t < 4; ++t) {
      af[t] = *(const bf16x8*)&Asm[(ar + t * 16) * BK + ak];
      bfr[t] = *(const bf16x8*)&Bsm[(br + t * 16) * BK + ak];
    }
#pragma unroll
    for (int mi = 0; mi < 4; ++mi)
#pragma unroll
      for (int ni = 0; ni < 4; ++ni)
        acc[mi][ni] = __builtin_amdgcn_mfma_f32_16x16x32_bf16(
            af[mi], bfr[ni], acc[mi][ni], 0, 0, 0);
    __syncthreads();
  }

  const int rb = (lane >> 4) * 4;
  const int cb = lane & 15;
#pragma unroll
  for (int ni = 0; ni < 4; ++ni) {
    const int gcol = n0 + wc + ni * 16 + cb;
#pragma unroll
    for (int mi = 0; mi < 4; ++mi) {
      const int growb = m0 + wr + mi * 16 + rb;
#pragma unroll
      for (int j = 0; j < 4; ++j) {
        const size_t grow = (size_t)(growb + j);
        logits[(grow * L_ + i) * A_ + gcol] = acc[mi][ni][j];
      }
    }
  }
}

// ---------------------------------------------------------------------------
extern "C" void kernel_launch(void* const* d_in, const int* in_sizes, int n_in,
                              void* d_out, int out_size, void* d_ws,
                              size_t ws_size, hipStream_t stream) {
  (void)in_sizes; (void)n_in; (void)out_size; (void)ws_size;
  const float* x = (const float*)d_in[0];
  const float* mean = (const float*)d_in[1];
  const float* stdv = (const float*)d_in[2];
  const float* Wenc = (const float*)d_in[3];
  const float* theta = (const float*)d_in[4];
  const float* Wdec = (const float*)d_in[5];

  float* logits = (float*)d_out;
  float* enc = (float*)d_out + (size_t)B_ * L_ * A_;

  char* ws = (char*)d_ws;
  const size_t actBytes = (size_t)L_ * B_ * F_ * 2;      // 402.7 MB
  const size_t sxBytes = (size_t)L_ * B_ * A_ * 2;       // 75.5 MB
  unsigned short* act = (unsigned short*)ws;
  unsigned short* sx = (unsigned short*)(ws + actBytes);
  unsigned short* wencT = (unsigned short*)(ws + actBytes + sxBytes);
  // W_dec^T is only needed after the encoder; alias it over sx/wencT.
  unsigned short* wdecT = (unsigned short*)(ws + actBytes);

  prep_sx<<<(B_ * L_ * A_ / 4 + 255) / 256, 256, 0, stream>>>(x, mean, stdv, sx);
  transpose_cvt<<<dim3(F_ / 32, A_ / 32, L_), dim3(32, 8), 0, stream>>>(
      Wenc, wencT, A_, F_);
  enc_gemm<<<dim3(B_ / BM, F_ / BN, L_), 256, 0, stream>>>(
      sx, wencT, theta, enc, act);
  transpose_cvt<<<dim3(A_ / 32, F_ / 32, NTRI), dim3(32, 8), 0, stream>>>(
      Wdec, wdecT, F_, A_);
  dec_gemm<<<dim3(B_ / BM, A_ / BN, L_), 256, 0, stream>>>(act, wdecT, logits);
}

// Round 3
// 3000.836 us; speedup vs baseline: 1.6288x; 1.6288x over previous
//
#include <hip/hip_runtime.h>
#include <cstdint>
#include <cstddef>

#define B_ 4096
#define L_ 12
#define A_ 768
#define F_ 4096
#define NTRI 78

typedef __bf16 bf16x8 __attribute__((ext_vector_type(8)));
typedef float f32x4 __attribute__((ext_vector_type(4)));
typedef unsigned short u16x4 __attribute__((ext_vector_type(4)));

__device__ __forceinline__ unsigned short f32_to_bf16(float f) {
  unsigned int u = __float_as_uint(f);
  u += 0x7fffu + ((u >> 16) & 1u);   // round-to-nearest-even
  return (unsigned short)(u >> 16);
}

__device__ __forceinline__ void gload_lds16(const void* g, void* l) {
  __builtin_amdgcn_global_load_lds(
      (const __attribute__((address_space(1))) void*)g,
      (__attribute__((address_space(3))) void*)l,
      16, 0, 0);
}

// ---------------------------------------------------------------------------
// prep_sx: sx[l][b][a] = (x[b][l][a] - mean[l][a]) / std[l][a]  (bf16)
// ---------------------------------------------------------------------------
__global__ __launch_bounds__(256) void prep_sx(
    const float* __restrict__ x, const float* __restrict__ mean,
    const float* __restrict__ stdv, unsigned short* __restrict__ sx) {
  size_t i4 = (size_t)blockIdx.x * 256 + threadIdx.x;
  size_t e = i4 * 4;
  if (e >= (size_t)B_ * L_ * A_) return;
  unsigned int a = (unsigned int)(e % A_);
  unsigned int t = (unsigned int)(e / A_);
  unsigned int b = t / L_;
  unsigned int l = t % L_;
  float4 xv = *(const float4*)(x + e);
  float4 mv = *(const float4*)(mean + (size_t)l * A_ + a);
  float4 sv = *(const float4*)(stdv + (size_t)l * A_ + a);
  u16x4 o;
  o.x = f32_to_bf16((xv.x - mv.x) / sv.x);
  o.y = f32_to_bf16((xv.y - mv.y) / sv.y);
  o.z = f32_to_bf16((xv.z - mv.z) / sv.z);
  o.w = f32_to_bf16((xv.w - mv.w) / sv.w);
  *(u16x4*)(sx + ((size_t)l * B_ + b) * A_ + a) = o;
}

// ---------------------------------------------------------------------------
// transpose_cvt: per matrix z (R x C f32, row-major) -> out (C x R bf16)
// ---------------------------------------------------------------------------
__global__ __launch_bounds__(256) void transpose_cvt(
    const float* __restrict__ in, unsigned short* __restrict__ out,
    int R, int C) {
  __shared__ float tile[32][33];
  const float* inz = in + (size_t)blockIdx.z * R * C;
  unsigned short* outz = out + (size_t)blockIdx.z * R * C;
  int c0 = blockIdx.x * 32, r0 = blockIdx.y * 32;
  int tx = threadIdx.x, ty = threadIdx.y;
#pragma unroll
  for (int q = 0; q < 4; ++q) {
    int r = ty + q * 8;
    tile[r][tx] = inz[(size_t)(r0 + r) * C + (c0 + tx)];
  }
  __syncthreads();
#pragma unroll
  for (int q = 0; q < 4; ++q) {
    int r = ty + q * 8;
    outz[(size_t)(c0 + r) * R + (r0 + tx)] = f32_to_bf16(tile[tx][r]);
  }
}

// ---------------------------------------------------------------------------
// 8-wave 256x256-tile GEMM core, BK=32, ring-4 LDS, prefetch distance 3.
// LDS layout per operand: 4 slots x [256 rows][32 k] bf16 (64 B rows), with
// 16B-slot XOR swizzle  phys_slot = logical_slot ^ ((row>>1)&3)  applied on
// the *global source* address at stage time (LDS dest stays linear) and on
// the ds_read address at read time.
// Per K-tile: 2 phases x {ds_read frags ; stage 1 op-tile of kt+3 ; barrier ;
// setprio(1) ; 16 MFMA ; setprio(0) ; barrier}, counted vmcnt(8) at the
// boundary (4 vmem instr per wave per K-tile; tiles kt+2,kt+3 stay in flight).
// ---------------------------------------------------------------------------
__device__ __forceinline__ bf16x8 read_frag(const char* base, int row, int g) {
  int ss = g ^ ((row >> 1) & 3);
  return *(const bf16x8*)(base + row * 64 + ss * 16);
}

template <class FSrc>
__device__ __forceinline__ void stage_tile(FSrc src, int kt, char* ringbase,
                                           int w, int lane) {
  char* base = ringbase + (kt & 3) * 16384;
#pragma unroll
  for (int q = 0; q < 2; ++q) {
    int c = q * 8 + w;                 // 1 KiB chunk index, 0..15
    int row = c * 16 + (lane >> 2);    // 0..255
    int ss = (lane & 3) ^ ((row >> 1) & 3);
    gload_lds16(src(kt, row, ss * 8), base + c * 1024);
  }
}

template <class FA, class FB>
__device__ __forceinline__ void gemm_core(int KT, char* AS, char* BS, int w,
                                          int lane, int wr, int wc, FA srcA,
                                          FB srcB, f32x4 (&acc)[8][4]) {
  const int g = lane >> 4;
  const int fr = lane & 15;
  // prologue: stage K-tiles 0,1,2 (12 vmem instr); wait tile 0 (oldest 4)
  stage_tile(srcA, 0, AS, w, lane);
  stage_tile(srcB, 0, BS, w, lane);
  stage_tile(srcA, 1, AS, w, lane);
  stage_tile(srcB, 1, BS, w, lane);
  stage_tile(srcA, 2, AS, w, lane);
  stage_tile(srcB, 2, BS, w, lane);
  asm volatile("s_waitcnt vmcnt(8)" ::: "memory");
  __builtin_amdgcn_s_barrier();

  for (int kt = 0; kt < KT; ++kt) {
    const char* Ab = AS + (kt & 3) * 16384;
    const char* Bb = BS + (kt & 3) * 16384;
    bf16x8 bfr[4], afr[4];
    // ---- phase A: all B-frags + A-frags m0..3 ; stage A-tile of kt+3 ----
#pragma unroll
    for (int ni = 0; ni < 4; ++ni)
      bfr[ni] = read_frag(Bb, wc * 64 + ni * 16 + fr, g);
#pragma unroll
    for (int mi = 0; mi < 4; ++mi)
      afr[mi] = read_frag(Ab, wr * 128 + mi * 16 + fr, g);
    if (kt + 3 < KT) stage_tile(srcA, kt + 3, AS, w, lane);
    asm volatile("" ::: "memory");
    __builtin_amdgcn_s_barrier();
    __builtin_amdgcn_s_setprio(1);
#pragma unroll
    for (int mi = 0; mi < 4; ++mi)
#pragma unroll
      for (int ni = 0; ni < 4; ++ni)
        acc[mi][ni] = __builtin_amdgcn_mfma_f32_16x16x32_bf16(
            afr[mi], bfr[ni], acc[mi][ni], 0, 0, 0);
    __builtin_amdgcn_s_setprio(0);
    asm volatile("" ::: "memory");
    __builtin_amdgcn_s_barrier();
    // ---- phase B: A-frags m4..7 ; stage B-tile of kt+3 ----
#pragma unroll
    for (int mi = 0; mi < 4; ++mi)
      afr[mi] = read_frag(Ab, wr * 128 + (mi + 4) * 16 + fr, g);
    if (kt + 3 < KT) stage_tile(srcB, kt + 3, BS, w, lane);
    asm volatile("" ::: "memory");
    __builtin_amdgcn_s_barrier();
    __builtin_amdgcn_s_setprio(1);
#pragma unroll
    for (int mi = 0; mi < 4; ++mi)
#pragma unroll
      for (int ni = 0; ni < 4; ++ni)
        acc[mi + 4][ni] = __builtin_amdgcn_mfma_f32_16x16x32_bf16(
            afr[mi], bfr[ni], acc[mi + 4][ni], 0, 0, 0);
    __builtin_amdgcn_s_setprio(0);
    // ---- K-tile boundary: ensure tile kt+1 landed; keep kt+2,kt+3 in flight
    if (kt + 3 < KT)      { asm volatile("s_waitcnt vmcnt(8)" ::: "memory"); }
    else if (kt + 2 < KT) { asm volatile("s_waitcnt vmcnt(4)" ::: "memory"); }
    else if (kt + 1 < KT) { asm volatile("s_waitcnt vmcnt(0)" ::: "memory"); }
    asm volatile("" ::: "memory");
    __builtin_amdgcn_s_barrier();
  }
}

// ---------------------------------------------------------------------------
// Encoder: enc[b,l,f] = sum_a sx[l,b,a] * WencT[l,f,a]; act = JumpReLU(enc)
// grid 3072 = 12 layers x (16 m x 16 n), chunked XCD swizzle (3072 % 8 == 0)
// ---------------------------------------------------------------------------
__global__ __launch_bounds__(512, 2) void enc_gemm8(
    const unsigned short* __restrict__ sxT,   // (L,B,A)
    const unsigned short* __restrict__ wT,    // (L,F,A)
    const float* __restrict__ theta,          // (L,F)
    float* __restrict__ enc_out,              // (B,L,F)
    unsigned short* __restrict__ act)         // (L,B,F)
{
  extern __shared__ __align__(16) char lds[];
  char* AS = lds;
  char* BS = lds + 65536;
  const int b = blockIdx.x;
  const int wg = (b & 7) * 384 + (b >> 3);   // contiguous chunk per XCD
  const int l = wg >> 8;                     // 0..11
  const int blk = wg & 255;
  const int m0 = (blk & 15) * 256;
  const int n0 = (blk >> 4) * 256;
  const int tid = threadIdx.x;
  const int w = tid >> 6, lane = tid & 63;
  const int wr = w >> 2, wc = w & 3;

  f32x4 acc[8][4] = {};
  auto srcA = [&](int kt, int row, int ce) {
    return sxT + ((size_t)l * B_ + m0 + row) * A_ + kt * 32 + ce;
  };
  auto srcB = [&](int kt, int row, int ce) {
    return wT + ((size_t)l * F_ + n0 + row) * A_ + kt * 32 + ce;
  };
  gemm_core(A_ / 32, AS, BS, w, lane, wr, wc, srcA, srcB, acc);

  const int g = lane >> 4, fr = lane & 15;
#pragma unroll
  for (int ni = 0; ni < 4; ++ni) {
    const int gcol = n0 + wc * 64 + ni * 16 + fr;
    const float th = theta[(size_t)l * F_ + gcol];
#pragma unroll
    for (int mi = 0; mi < 8; ++mi) {
      const int growb = m0 + wr * 128 + mi * 16 + g * 4;
#pragma unroll
      for (int jj = 0; jj < 4; ++jj) {
        const float v = acc[mi][ni][jj];
        const size_t grow = (size_t)(growb + jj);
        enc_out[(grow * L_ + l) * F_ + gcol] = v;
        act[((size_t)l * B_ + grow) * F_ + gcol] =
            (v > th) ? f32_to_bf16(v) : (unsigned short)0;
      }
    }
  }
}

// ---------------------------------------------------------------------------
// Decoder: logits[b,i,a] = sum_{l<=i} sum_f act[l,b,f] * WdecT[tri(i,l),a,f]
// grid 576 = 12 layers x (16 m x 3 n). Work-balanced XCD decode: XCD x gets
// blocks x*6..x*6+5 of EVERY layer (equal sum(i+1) work per XCD), heavy
// layers first within each XCD.
// ---------------------------------------------------------------------------
__global__ __launch_bounds__(512, 2) void dec_gemm8(
    const unsigned short* __restrict__ act,    // (L,B,F)
    const unsigned short* __restrict__ wdecT,  // (NTRI,A,F)
    float* __restrict__ logits)                // (B,L,A)
{
  extern __shared__ __align__(16) char lds[];
  char* AS = lds;
  char* BS = lds + 65536;
  const int b = blockIdx.x;
  const int xcd = b & 7;
  const int idx = b >> 3;          // 0..71
  const int z = idx / 6;           // 0..11, heavy first
  const int j = idx - z * 6;
  const int i = 11 - z;
  const int blk = xcd * 6 + j;     // 0..47
  const int m0 = (blk & 15) * 256;
  const int n0 = (blk >> 4) * 256; // 0..2 -> {0,256,512}
  const int triBase = i * (i + 1) / 2;
  const int KT = (i + 1) * 128;
  const int tid = threadIdx.x;
  const int w = tid >> 6, lane = tid & 63;
  const int wr = w >> 2, wc = w & 3;

  f32x4 acc[8][4] = {};
  auto srcA = [&](int kt, int row, int ce) {
    int l = kt >> 7;
    int kk0 = (kt & 127) * 32;
    return act + ((size_t)l * B_ + m0 + row) * F_ + kk0 + ce;
  };
  auto srcB = [&](int kt, int row, int ce) {
    int l = kt >> 7;
    int kk0 = (kt & 127) * 32;
    return wdecT + ((size_t)(triBase + l) * A_ + n0 + row) * F_ + kk0 + ce;
  };
  gemm_core(KT, AS, BS, w, lane, wr, wc, srcA, srcB, acc);

  const int g = lane >> 4, fr = lane & 15;
#pragma unroll
  for (int mi = 0; mi < 8; ++mi) {
    const int growb = m0 + wr * 128 + mi * 16 + g * 4;
#pragma unroll
    for (int ni = 0; ni < 4; ++ni) {
      const int gcol = n0 + wc * 64 + ni * 16 + fr;
#pragma unroll
      for (int jj = 0; jj < 4; ++jj)
        logits[((size_t)(growb + jj) * L_ + i) * A_ + gcol] = acc[mi][ni][jj];
    }
  }
}

// ---------------------------------------------------------------------------
extern "C" void kernel_launch(void* const* d_in, const int* in_sizes, int n_in,
                              void* d_out, int out_size, void* d_ws,
                              size_t ws_size, hipStream_t stream) {
  (void)in_sizes; (void)n_in; (void)out_size; (void)ws_size;
  const float* x = (const float*)d_in[0];
  const float* mean = (const float*)d_in[1];
  const float* stdv = (const float*)d_in[2];
  const float* Wenc = (const float*)d_in[3];
  const float* theta = (const float*)d_in[4];
  const float* Wdec = (const float*)d_in[5];

  float* logits = (float*)d_out;
  float* enc = (float*)d_out + (size_t)B_ * L_ * A_;

  char* ws = (char*)d_ws;
  const size_t actBytes = (size_t)L_ * B_ * F_ * 2;      // 402.7 MB
  const size_t sxBytes = (size_t)L_ * B_ * A_ * 2;       // 75.5 MB
  unsigned short* act = (unsigned short*)ws;
  unsigned short* sx = (unsigned short*)(ws + actBytes);
  unsigned short* wencT = (unsigned short*)(ws + actBytes + sxBytes);
  // W_dec^T only needed after the encoder; alias it over sx/wencT.
  unsigned short* wdecT = (unsigned short*)(ws + actBytes);

  hipFuncSetAttribute((const void*)enc_gemm8,
                      hipFuncAttributeMaxDynamicSharedMemorySize, 131072);
  hipFuncSetAttribute((const void*)dec_gemm8,
                      hipFuncAttributeMaxDynamicSharedMemorySize, 131072);

  prep_sx<<<(B_ * L_ * A_ / 4 + 255) / 256, 256, 0, stream>>>(x, mean, stdv, sx);
  transpose_cvt<<<dim3(F_ / 32, A_ / 32, L_), dim3(32, 8), 0, stream>>>(
      Wenc, wencT, A_, F_);
  enc_gemm8<<<3072, 512, 131072, stream>>>(sx, wencT, theta, enc, act);
  transpose_cvt<<<dim3(A_ / 32, F_ / 32, NTRI), dim3(32, 8), 0, stream>>>(
      Wdec, wdecT, F_, A_);
  dec_gemm8<<<576, 512, 131072, stream>>>(act, wdecT, logits);
}

// Round 4
// 2959.802 us; speedup vs baseline: 1.6513x; 1.0139x over previous
//
#include <hip/hip_runtime.h>
#include <cstdint>
#include <cstddef>

#define B_ 4096
#define L_ 12
#define A_ 768
#define F_ 4096
#define NTRI 78

typedef __bf16 bf16x8 __attribute__((ext_vector_type(8)));
typedef float f32x4 __attribute__((ext_vector_type(4)));
typedef unsigned short u16x4 __attribute__((ext_vector_type(4)));
typedef unsigned short u16x8 __attribute__((ext_vector_type(8)));

__device__ __forceinline__ unsigned short f32_to_bf16(float f) {
  unsigned int u = __float_as_uint(f);
  u += 0x7fffu + ((u >> 16) & 1u);   // round-to-nearest-even
  return (unsigned short)(u >> 16);
}

__device__ __forceinline__ void gload_lds16(const void* g, void* l) {
  __builtin_amdgcn_global_load_lds(
      (const __attribute__((address_space(1))) void*)g,
      (__attribute__((address_space(3))) void*)l,
      16, 0, 0);
}

// ---------------------------------------------------------------------------
// prep_sx: sx[l][b][a] = (x[b][l][a] - mean[l][a]) / std[l][a]  (bf16)
// ---------------------------------------------------------------------------
__global__ __launch_bounds__(256) void prep_sx(
    const float* __restrict__ x, const float* __restrict__ mean,
    const float* __restrict__ stdv, unsigned short* __restrict__ sx) {
  size_t i4 = (size_t)blockIdx.x * 256 + threadIdx.x;
  size_t e = i4 * 4;
  if (e >= (size_t)B_ * L_ * A_) return;
  unsigned int a = (unsigned int)(e % A_);
  unsigned int t = (unsigned int)(e / A_);
  unsigned int b = t / L_;
  unsigned int l = t % L_;
  float4 xv = *(const float4*)(x + e);
  float4 mv = *(const float4*)(mean + (size_t)l * A_ + a);
  float4 sv = *(const float4*)(stdv + (size_t)l * A_ + a);
  u16x4 o;
  o.x = f32_to_bf16((xv.x - mv.x) / sv.x);
  o.y = f32_to_bf16((xv.y - mv.y) / sv.y);
  o.z = f32_to_bf16((xv.z - mv.z) / sv.z);
  o.w = f32_to_bf16((xv.w - mv.w) / sv.w);
  *(u16x4*)(sx + ((size_t)l * B_ + b) * A_ + a) = o;
}

// ---------------------------------------------------------------------------
// transpose_cvt64: per z-slice (R x C f32, row-major) -> out (C x R bf16).
// 64x64 tiles, float4 loads, ushort8 stores, padded LDS (65) -> 2-way max.
// ---------------------------------------------------------------------------
__global__ __launch_bounds__(256) void transpose_cvt64(
    const float* __restrict__ in, unsigned short* __restrict__ out,
    int R, int C) {
  __shared__ float tile[64][65];
  const float* inz = in + (size_t)blockIdx.z * R * C;
  unsigned short* outz = out + (size_t)blockIdx.z * R * C;
  const int c0 = blockIdx.x * 64, r0 = blockIdx.y * 64;
  const int t = threadIdx.x;
  {
    const int c = (t & 15) * 4;
    const int rb = t >> 4;          // 0..15
#pragma unroll
    for (int q = 0; q < 4; ++q) {
      const int r = rb + q * 16;
      float4 v = *(const float4*)(inz + (size_t)(r0 + r) * C + (c0 + c));
      tile[r][c] = v.x; tile[r][c + 1] = v.y;
      tile[r][c + 2] = v.z; tile[r][c + 3] = v.w;
    }
  }
  __syncthreads();
  {
    const int c = t >> 2;           // 0..63 output row (C-dim)
    const int rb = (t & 3) * 16;    // 16 consecutive r
#pragma unroll
    for (int h = 0; h < 2; ++h) {
      u16x8 o;
#pragma unroll
      for (int j = 0; j < 8; ++j) o[j] = f32_to_bf16(tile[rb + h * 8 + j][c]);
      *(u16x8*)(outz + (size_t)(c0 + c) * R + (r0 + rb + h * 8)) = o;
    }
  }
}

// ---------------------------------------------------------------------------
// 8-wave 256x256-tile GEMM core, BK=32, ring-4 LDS, prefetch distance 3,
// register-double-buffered fragments, ONE barrier per K-tile.
// LDS per operand: 4 slots x [256 rows][32 k] bf16 (64 B rows), 16B-chunk XOR
// swizzle  phys_chunk = logical_chunk ^ ((row>>1)&3)  applied on the global
// source at stage time (LDS dest linear) and on the ds_read addr at read time.
// Iteration kt:  vmcnt(4) [tile kt+1 landed, kt+2 in flight] ; barrier ;
//   read A-hi frags(kt) ; stage tile kt+3 ; MFMA A-lo x B (compiler lgkmcnt) ;
//   prefetch B+A-lo frags(kt+1) ; MFMA A-hi x B ; swap reg buffers.
// Slot-reuse proof: frags of slot (kt-1)&3 are fully read before the MFMA
// bursts of iteration kt-1 (compiler waits), hence before the top barrier of
// iteration kt; the stage into that slot is issued after that barrier.
// ---------------------------------------------------------------------------
__device__ __forceinline__ bf16x8 read_frag(const char* base, int row, int g) {
  int ss = g ^ ((row >> 1) & 3);
  return *(const bf16x8*)(base + row * 64 + ss * 16);
}

template <class FSrc>
__device__ __forceinline__ void stage_tile(FSrc src, int kt, char* ringbase,
                                           int w, int lane) {
  char* base = ringbase + (kt & 3) * 16384;
#pragma unroll
  for (int q = 0; q < 2; ++q) {
    int c = q * 8 + w;                 // 1 KiB chunk index, 0..15
    int row = c * 16 + (lane >> 2);    // 0..255
    int ss = (lane & 3) ^ ((row >> 1) & 3);
    gload_lds16(src(kt, row, ss * 8), base + c * 1024);
  }
}

template <class FA, class FB>
__device__ __forceinline__ void gemm_core(int KT, char* AS, char* BS, int w,
                                          int lane, int wr, int wc, FA srcA,
                                          FB srcB, f32x4 (&acc)[8][4]) {
  const int g = lane >> 4;
  const int fr = lane & 15;
  // prologue: stage K-tiles 0,1,2 (12 vmem); publish tile 0; preload frags(0)
  stage_tile(srcA, 0, AS, w, lane);
  stage_tile(srcB, 0, BS, w, lane);
  stage_tile(srcA, 1, AS, w, lane);
  stage_tile(srcB, 1, BS, w, lane);
  stage_tile(srcA, 2, AS, w, lane);
  stage_tile(srcB, 2, BS, w, lane);
  asm volatile("s_waitcnt vmcnt(8)" ::: "memory");
  __builtin_amdgcn_s_barrier();

  bf16x8 bcur[4], a0cur[4], a1[4], bnxt[4], a0nxt[4];
#pragma unroll
  for (int ni = 0; ni < 4; ++ni)
    bcur[ni] = read_frag(BS, wc * 64 + ni * 16 + fr, g);
#pragma unroll
  for (int mi = 0; mi < 4; ++mi)
    a0cur[mi] = read_frag(AS, wr * 128 + mi * 16 + fr, g);

  for (int kt = 0; kt < KT; ++kt) {
    const char* Ab = AS + (kt & 3) * 16384;
    const char* Bb = BS + (kt & 3) * 16384;
    const char* Abn = AS + ((kt + 1) & 3) * 16384;
    const char* Bbn = BS + ((kt + 1) & 3) * 16384;
    // publish tile kt+1 (kt+2 stays in flight); free slot (kt-1)&3
    if (kt + 2 < KT) { asm volatile("s_waitcnt vmcnt(4)" ::: "memory"); }
    else             { asm volatile("s_waitcnt vmcnt(0)" ::: "memory"); }
    __builtin_amdgcn_s_barrier();
    // A-hi frags of current tile
#pragma unroll
    for (int mi = 0; mi < 4; ++mi)
      a1[mi] = read_frag(Ab, wr * 128 + (mi + 4) * 16 + fr, g);
    // stage tile kt+3 into slot (kt-1)&3
    if (kt + 3 < KT) {
      stage_tile(srcA, kt + 3, AS, w, lane);
      stage_tile(srcB, kt + 3, BS, w, lane);
    }
    __builtin_amdgcn_s_setprio(1);
#pragma unroll
    for (int mi = 0; mi < 4; ++mi)
#pragma unroll
      for (int ni = 0; ni < 4; ++ni)
        acc[mi][ni] = __builtin_amdgcn_mfma_f32_16x16x32_bf16(
            a0cur[mi], bcur[ni], acc[mi][ni], 0, 0, 0);
    __builtin_amdgcn_s_setprio(0);
    // prefetch frags of tile kt+1 (published at this iteration's barrier)
    if (kt + 1 < KT) {
#pragma unroll
      for (int ni = 0; ni < 4; ++ni)
        bnxt[ni] = read_frag(Bbn, wc * 64 + ni * 16 + fr, g);
#pragma unroll
      for (int mi = 0; mi < 4; ++mi)
        a0nxt[mi] = read_frag(Abn, wr * 128 + mi * 16 + fr, g);
    }
    __builtin_amdgcn_s_setprio(1);
#pragma unroll
    for (int mi = 0; mi < 4; ++mi)
#pragma unroll
      for (int ni = 0; ni < 4; ++ni)
        acc[mi + 4][ni] = __builtin_amdgcn_mfma_f32_16x16x32_bf16(
            a1[mi], bcur[ni], acc[mi + 4][ni], 0, 0, 0);
    __builtin_amdgcn_s_setprio(0);
#pragma unroll
    for (int q = 0; q < 4; ++q) {
      bcur[q] = bnxt[q];
      a0cur[q] = a0nxt[q];
    }
  }
}

// ---------------------------------------------------------------------------
// Encoder: enc[b,l,f] = sum_a sx[l,b,a] * WencT[l,f,a]; act = JumpReLU(enc)
// grid 3072 = 12 layers x (16 m x 16 n), chunked XCD swizzle (3072 % 8 == 0)
// ---------------------------------------------------------------------------
__global__ __launch_bounds__(512, 2) void enc_gemm8(
    const unsigned short* __restrict__ sxT,   // (L,B,A)
    const unsigned short* __restrict__ wT,    // (L,F,A)
    const float* __restrict__ theta,          // (L,F)
    float* __restrict__ enc_out,              // (B,L,F)
    unsigned short* __restrict__ act)         // (L,B,F)
{
  extern __shared__ __align__(16) char lds[];
  char* AS = lds;
  char* BS = lds + 65536;
  const int b = blockIdx.x;
  const int wg = (b & 7) * 384 + (b >> 3);   // contiguous chunk per XCD
  const int l = wg >> 8;                     // 0..11
  const int blk = wg & 255;
  const int m0 = (blk & 15) * 256;
  const int n0 = (blk >> 4) * 256;
  const int tid = threadIdx.x;
  const int w = tid >> 6, lane = tid & 63;
  const int wr = w >> 2, wc = w & 3;

  f32x4 acc[8][4] = {};
  auto srcA = [&](int kt, int row, int ce) {
    return sxT + ((size_t)l * B_ + m0 + row) * A_ + kt * 32 + ce;
  };
  auto srcB = [&](int kt, int row, int ce) {
    return wT + ((size_t)l * F_ + n0 + row) * A_ + kt * 32 + ce;
  };
  gemm_core(A_ / 32, AS, BS, w, lane, wr, wc, srcA, srcB, acc);

  const int g = lane >> 4, fr = lane & 15;
#pragma unroll
  for (int ni = 0; ni < 4; ++ni) {
    const int gcol = n0 + wc * 64 + ni * 16 + fr;
    const float th = theta[(size_t)l * F_ + gcol];
#pragma unroll
    for (int mi = 0; mi < 8; ++mi) {
      const int growb = m0 + wr * 128 + mi * 16 + g * 4;
#pragma unroll
      for (int jj = 0; jj < 4; ++jj) {
        const float v = acc[mi][ni][jj];
        const size_t grow = (size_t)(growb + jj);
        enc_out[(grow * L_ + l) * F_ + gcol] = v;
        act[((size_t)l * B_ + grow) * F_ + gcol] =
            (v > th) ? f32_to_bf16(v) : (unsigned short)0;
      }
    }
  }
}

// ---------------------------------------------------------------------------
// Decoder: logits[b,i,a] = sum_{l<=i} sum_f act[l,b,f] * WdecT[tri(i,l),a,f]
// grid 576 = 12 layers x (16 m x 3 n). Work-balanced XCD decode: XCD x gets
// blocks x*6..x*6+5 of EVERY layer (equal sum(i+1) work per XCD), heavy
// layers first within each XCD.
// ---------------------------------------------------------------------------
__global__ __launch_bounds__(512, 2) void dec_gemm8(
    const unsigned short* __restrict__ act,    // (L,B,F)
    const unsigned short* __restrict__ wdecT,  // (NTRI,A,F)
    float* __restrict__ logits)                // (B,L,A)
{
  extern __shared__ __align__(16) char lds[];
  char* AS = lds;
  char* BS = lds + 65536;
  const int b = blockIdx.x;
  const int xcd = b & 7;
  const int idx = b >> 3;          // 0..71
  const int z = idx / 6;           // 0..11, heavy first
  const int j = idx - z * 6;
  const int i = 11 - z;
  const int blk = xcd * 6 + j;     // 0..47
  const int m0 = (blk & 15) * 256;
  const int n0 = (blk >> 4) * 256; // 0..2 -> {0,256,512}
  const int triBase = i * (i + 1) / 2;
  const int KT = (i + 1) * 128;
  const int tid = threadIdx.x;
  const int w = tid >> 6, lane = tid & 63;
  const int wr = w >> 2, wc = w & 3;

  f32x4 acc[8][4] = {};
  auto srcA = [&](int kt, int row, int ce) {
    int l = kt >> 7;
    int kk0 = (kt & 127) * 32;
    return act + ((size_t)l * B_ + m0 + row) * F_ + kk0 + ce;
  };
  auto srcB = [&](int kt, int row, int ce) {
    int l = kt >> 7;
    int kk0 = (kt & 127) * 32;
    return wdecT + ((size_t)(triBase + l) * A_ + n0 + row) * F_ + kk0 + ce;
  };
  gemm_core(KT, AS, BS, w, lane, wr, wc, srcA, srcB, acc);

  const int g = lane >> 4, fr = lane & 15;
#pragma unroll
  for (int mi = 0; mi < 8; ++mi) {
    const int growb = m0 + wr * 128 + mi * 16 + g * 4;
#pragma unroll
    for (int ni = 0; ni < 4; ++ni) {
      const int gcol = n0 + wc * 64 + ni * 16 + fr;
#pragma unroll
      for (int jj = 0; jj < 4; ++jj)
        logits[((size_t)(growb + jj) * L_ + i) * A_ + gcol] = acc[mi][ni][jj];
    }
  }
}

// ---------------------------------------------------------------------------
extern "C" void kernel_launch(void* const* d_in, const int* in_sizes, int n_in,
                              void* d_out, int out_size, void* d_ws,
                              size_t ws_size, hipStream_t stream) {
  (void)in_sizes; (void)n_in; (void)out_size; (void)ws_size;
  const float* x = (const float*)d_in[0];
  const float* mean = (const float*)d_in[1];
  const float* stdv = (const float*)d_in[2];
  const float* Wenc = (const float*)d_in[3];
  const float* theta = (const float*)d_in[4];
  const float* Wdec = (const float*)d_in[5];

  float* logits = (float*)d_out;
  float* enc = (float*)d_out + (size_t)B_ * L_ * A_;

  char* ws = (char*)d_ws;
  const size_t actBytes = (size_t)L_ * B_ * F_ * 2;      // 402.7 MB
  const size_t sxBytes = (size_t)L_ * B_ * A_ * 2;       // 75.5 MB
  unsigned short* act = (unsigned short*)ws;
  unsigned short* sx = (unsigned short*)(ws + actBytes);
  unsigned short* wencT = (unsigned short*)(ws + actBytes + sxBytes);
  // W_dec^T only needed after the encoder; alias it over sx/wencT.
  unsigned short* wdecT = (unsigned short*)(ws + actBytes);

  hipFuncSetAttribute((const void*)enc_gemm8,
                      hipFuncAttributeMaxDynamicSharedMemorySize, 131072);
  hipFuncSetAttribute((const void*)dec_gemm8,
                      hipFuncAttributeMaxDynamicSharedMemorySize, 131072);

  prep_sx<<<(B_ * L_ * A_ / 4 + 255) / 256, 256, 0, stream>>>(x, mean, stdv, sx);
  transpose_cvt64<<<dim3(F_ / 64, A_ / 64, L_), 256, 0, stream>>>(
      Wenc, wencT, A_, F_);
  enc_gemm8<<<3072, 512, 131072, stream>>>(sx, wencT, theta, enc, act);
  transpose_cvt64<<<dim3(A_ / 64, F_ / 64, NTRI), 256, 0, stream>>>(
      Wdec, wdecT, F_, A_);
  dec_gemm8<<<576, 512, 131072, stream>>>(act, wdecT, logits);
}

// Round 5
// 2825.591 us; speedup vs baseline: 1.7298x; 1.0475x over previous
//
#include <hip/hip_runtime.h>
#include <cstdint>
#include <cstddef>

#define B_ 4096
#define L_ 12
#define A_ 768
#define F_ 4096
#define NTRI 78

typedef __bf16 bf16x8 __attribute__((ext_vector_type(8)));
typedef float f32x4 __attribute__((ext_vector_type(4)));
typedef unsigned short u16x4 __attribute__((ext_vector_type(4)));
typedef unsigned short u16x8 __attribute__((ext_vector_type(8)));

__device__ __forceinline__ unsigned short f32_to_bf16(float f) {
  unsigned int u = __float_as_uint(f);
  u += 0x7fffu + ((u >> 16) & 1u);   // round-to-nearest-even
  return (unsigned short)(u >> 16);
}

__device__ __forceinline__ void gload_lds16(const void* g, void* l) {
  __builtin_amdgcn_global_load_lds(
      (const __attribute__((address_space(1))) void*)g,
      (__attribute__((address_space(3))) void*)l,
      16, 0, 0);
}

// ---------------------------------------------------------------------------
// prep_sx: sx[l][b][a] = (x[b][l][a] - mean[l][a]) / std[l][a]  (bf16)
// ---------------------------------------------------------------------------
__global__ __launch_bounds__(256) void prep_sx(
    const float* __restrict__ x, const float* __restrict__ mean,
    const float* __restrict__ stdv, unsigned short* __restrict__ sx) {
  size_t i4 = (size_t)blockIdx.x * 256 + threadIdx.x;
  size_t e = i4 * 4;
  if (e >= (size_t)B_ * L_ * A_) return;
  unsigned int a = (unsigned int)(e % A_);
  unsigned int t = (unsigned int)(e / A_);
  unsigned int b = t / L_;
  unsigned int l = t % L_;
  float4 xv = *(const float4*)(x + e);
  float4 mv = *(const float4*)(mean + (size_t)l * A_ + a);
  float4 sv = *(const float4*)(stdv + (size_t)l * A_ + a);
  u16x4 o;
  o.x = f32_to_bf16((xv.x - mv.x) / sv.x);
  o.y = f32_to_bf16((xv.y - mv.y) / sv.y);
  o.z = f32_to_bf16((xv.z - mv.z) / sv.z);
  o.w = f32_to_bf16((xv.w - mv.w) / sv.w);
  *(u16x4*)(sx + ((size_t)l * B_ + b) * A_ + a) = o;
}

// ---------------------------------------------------------------------------
// transpose_cvt64: per z-slice (R x C f32, row-major) -> out (C x R bf16).
// ---------------------------------------------------------------------------
__global__ __launch_bounds__(256) void transpose_cvt64(
    const float* __restrict__ in, unsigned short* __restrict__ out,
    int R, int C) {
  __shared__ float tile[64][65];
  const float* inz = in + (size_t)blockIdx.z * R * C;
  unsigned short* outz = out + (size_t)blockIdx.z * R * C;
  const int c0 = blockIdx.x * 64, r0 = blockIdx.y * 64;
  const int t = threadIdx.x;
  {
    const int c = (t & 15) * 4;
    const int rb = t >> 4;
#pragma unroll
    for (int q = 0; q < 4; ++q) {
      const int r = rb + q * 16;
      float4 v = *(const float4*)(inz + (size_t)(r0 + r) * C + (c0 + c));
      tile[r][c] = v.x; tile[r][c + 1] = v.y;
      tile[r][c + 2] = v.z; tile[r][c + 3] = v.w;
    }
  }
  __syncthreads();
  {
    const int c = t >> 2;
    const int rb = (t & 3) * 16;
#pragma unroll
    for (int h = 0; h < 2; ++h) {
      u16x8 o;
#pragma unroll
      for (int j = 0; j < 8; ++j) o[j] = f32_to_bf16(tile[rb + h * 8 + j][c]);
      *(u16x8*)(outz + (size_t)(c0 + c) * R + (r0 + rb + h * 8)) = o;
    }
  }
}

// ---------------------------------------------------------------------------
// 8-wave 256x256-tile GEMM core, BK=64, ring-2 LDS (m201 geometry),
// 4 phases per K-tile, 2 barriers per phase, setprio around each 16-MFMA
// cluster, vmcnt(0) only at phase-4 end (loads are then ~3 phases old).
// LDS per operand: 2 bufs x [256 rows][64 k] bf16 (128 B rows) = 64 KiB;
// 16B-chunk XOR swizzle: phys_chunk8 = logical_chunk8 ^ (row & 7), applied
// on the global source at stage time (LDS dest linear) and on ds_read addrs.
// Phase p reads feed phase p's MFMA; lgkmcnt auto-inserted by compiler; the
// wave stagger across the per-phase barriers overlaps LDS reads with MFMA.
// Ring-2 safety: stage(kt+1) at p1/p2 targets buf^1, whose tile-(kt-1) reads
// all retired before the previous K-tile's closing barrier; publish of tile
// kt+1 is vmcnt(0)+barrier at p4 end.
// ---------------------------------------------------------------------------
template <class KOffA, class KOffB>
__device__ __forceinline__ void gemm_core64(
    int KT, char* AS, char* BS,
    const char* gA0, const char* gB0, int ldA, int ldB,
    int w, int wr, int wc, int lane,
    KOffA koffA, KOffB koffB, f32x4 (&acc)[8][4]) {
  const int g = lane >> 4;
  const int fr = lane & 15;
  const int f7 = fr & 7;
  const uint32_t aRow = (uint32_t)(wr * 128 + fr) * 128;
  const uint32_t bRow = (uint32_t)(wc * 64 + fr) * 128;
  const uint32_t c0 = (uint32_t)((g ^ f7) * 16);
  const uint32_t c1 = (uint32_t)(((4 | g) ^ f7) * 16);
  const uint32_t aOff0 = aRow + c0, aOff1 = aRow + c1;
  const uint32_t bOff0 = bRow + c0, bOff1 = bRow + c1;

  auto stageA = [&](int kt) {
    uint32_t off = koffA(kt);
    char* d = AS + ((kt & 1) << 15) + (w << 10);
#pragma unroll
    for (int q = 0; q < 4; ++q)
      gload_lds16(gA0 + off + (uint32_t)q * 64u * (uint32_t)ldA, d + q * 8192);
  };
  auto stageB = [&](int kt) {
    uint32_t off = koffB(kt);
    char* d = BS + ((kt & 1) << 15) + (w << 10);
#pragma unroll
    for (int q = 0; q < 4; ++q)
      gload_lds16(gB0 + off + (uint32_t)q * 64u * (uint32_t)ldB, d + q * 8192);
  };

  // prologue: stage tile 0 into buf 0, publish.
  stageA(0);
  stageB(0);
  asm volatile("s_waitcnt vmcnt(0)" ::: "memory");
  __builtin_amdgcn_s_barrier();

  bf16x8 bk[4], aA[4], aB[4];
  for (int kt = 0; kt < KT; ++kt) {
    const char* Ab = AS + ((kt & 1) << 15);
    const char* Bb = BS + ((kt & 1) << 15);
    const bool more = (kt + 1 < KT);
    // ---- phase 1: B k0-frags + A lo k0-frags ; stage A(kt+1) ; q1 ----
#pragma unroll
    for (int ni = 0; ni < 4; ++ni)
      bk[ni] = *(const bf16x8*)(Bb + bOff0 + ni * 2048);
#pragma unroll
    for (int mi = 0; mi < 4; ++mi)
      aA[mi] = *(const bf16x8*)(Ab + aOff0 + mi * 2048);
    if (more) stageA(kt + 1);
    asm volatile("" ::: "memory");
    __builtin_amdgcn_s_barrier();
    __builtin_amdgcn_s_setprio(1);
#pragma unroll
    for (int mi = 0; mi < 4; ++mi)
#pragma unroll
      for (int ni = 0; ni < 4; ++ni)
        acc[mi][ni] = __builtin_amdgcn_mfma_f32_16x16x32_bf16(
            aA[mi], bk[ni], acc[mi][ni], 0, 0, 0);
    __builtin_amdgcn_s_setprio(0);
    asm volatile("" ::: "memory");
    __builtin_amdgcn_s_barrier();
    // ---- phase 2: A hi k0-frags ; stage B(kt+1) ; q2 ----
#pragma unroll
    for (int mi = 0; mi < 4; ++mi)
      aB[mi] = *(const bf16x8*)(Ab + aOff0 + (4 + mi) * 2048);
    if (more) stageB(kt + 1);
    asm volatile("" ::: "memory");
    __builtin_amdgcn_s_barrier();
    __builtin_amdgcn_s_setprio(1);
#pragma unroll
    for (int mi = 0; mi < 4; ++mi)
#pragma unroll
      for (int ni = 0; ni < 4; ++ni)
        acc[mi + 4][ni] = __builtin_amdgcn_mfma_f32_16x16x32_bf16(
            aB[mi], bk[ni], acc[mi + 4][ni], 0, 0, 0);
    __builtin_amdgcn_s_setprio(0);
    asm volatile("" ::: "memory");
    __builtin_amdgcn_s_barrier();
    // ---- phase 3: B k1-frags + A lo k1-frags ; q3 ----
#pragma unroll
    for (int ni = 0; ni < 4; ++ni)
      bk[ni] = *(const bf16x8*)(Bb + bOff1 + ni * 2048);
#pragma unroll
    for (int mi = 0; mi < 4; ++mi)
      aA[mi] = *(const bf16x8*)(Ab + aOff1 + mi * 2048);
    asm volatile("" ::: "memory");
    __builtin_amdgcn_s_barrier();
    __builtin_amdgcn_s_setprio(1);
#pragma unroll
    for (int mi = 0; mi < 4; ++mi)
#pragma unroll
      for (int ni = 0; ni < 4; ++ni)
        acc[mi][ni] = __builtin_amdgcn_mfma_f32_16x16x32_bf16(
            aA[mi], bk[ni], acc[mi][ni], 0, 0, 0);
    __builtin_amdgcn_s_setprio(0);
    asm volatile("" ::: "memory");
    __builtin_amdgcn_s_barrier();
    // ---- phase 4: A hi k1-frags ; q4 ; publish tile kt+1 ----
#pragma unroll
    for (int mi = 0; mi < 4; ++mi)
      aB[mi] = *(const bf16x8*)(Ab + aOff1 + (4 + mi) * 2048);
    asm volatile("" ::: "memory");
    __builtin_amdgcn_s_barrier();
    __builtin_amdgcn_s_setprio(1);
#pragma unroll
    for (int mi = 0; mi < 4; ++mi)
#pragma unroll
      for (int ni = 0; ni < 4; ++ni)
        acc[mi + 4][ni] = __builtin_amdgcn_mfma_f32_16x16x32_bf16(
            aB[mi], bk[ni], acc[mi + 4][ni], 0, 0, 0);
    __builtin_amdgcn_s_setprio(0);
    asm volatile("s_waitcnt vmcnt(0)" ::: "memory");
    __builtin_amdgcn_s_barrier();
  }
}

// ---------------------------------------------------------------------------
// Encoder: enc[b,l,f] = sum_a sx[l,b,a] * WencT[l,f,a]; act = JumpReLU(enc)
// grid 3072 = 12 layers x (16 m x 16 n), chunked XCD swizzle (3072 % 8 == 0)
// ---------------------------------------------------------------------------
__global__ __launch_bounds__(512, 2) void enc_gemm8(
    const unsigned short* __restrict__ sxT,   // (L,B,A)
    const unsigned short* __restrict__ wT,    // (L,F,A)
    const float* __restrict__ theta,          // (L,F)
    float* __restrict__ enc_out,              // (B,L,F)
    unsigned short* __restrict__ act)         // (L,B,F)
{
  extern __shared__ __align__(16) char lds[];
  char* AS = lds;
  char* BS = lds + 65536;
  const int b = blockIdx.x;
  const int wg = (b & 7) * 384 + (b >> 3);
  const int l = wg >> 8;
  const int blk = wg & 255;
  const int m0 = (blk & 15) * 256;
  const int n0 = (blk >> 4) * 256;
  const int tid = threadIdx.x;
  const int w = tid >> 6, lane = tid & 63;
  const int wr = w >> 2, wc = w & 3;
  const int sg = (lane & 7) ^ (lane >> 3);
  const int srow = w * 8 + (lane >> 3);

  const char* gA0 = (const char*)sxT +
      ((size_t)l * B_ + m0 + srow) * (A_ * 2) + sg * 16;
  const char* gB0 = (const char*)wT +
      ((size_t)l * F_ + n0 + srow) * (A_ * 2) + sg * 16;

  f32x4 acc[8][4] = {};
  auto koffA = [](int kt) { return (uint32_t)kt * 128u; };
  auto koffB = [](int kt) { return (uint32_t)kt * 128u; };
  gemm_core64(A_ / 64, AS, BS, gA0, gB0, A_ * 2, A_ * 2, w, wr, wc, lane,
              koffA, koffB, acc);

  const int g = lane >> 4, fr = lane & 15;
#pragma unroll
  for (int ni = 0; ni < 4; ++ni) {
    const int gcol = n0 + wc * 64 + ni * 16 + fr;
    const float th = theta[(size_t)l * F_ + gcol];
#pragma unroll
    for (int mi = 0; mi < 8; ++mi) {
      const int growb = m0 + wr * 128 + mi * 16 + g * 4;
#pragma unroll
      for (int jj = 0; jj < 4; ++jj) {
        const float v = acc[mi][ni][jj];
        const size_t grow = (size_t)(growb + jj);
        enc_out[(grow * L_ + l) * F_ + gcol] = v;
        act[((size_t)l * B_ + grow) * F_ + gcol] =
            (v > th) ? f32_to_bf16(v) : (unsigned short)0;
      }
    }
  }
}

// ---------------------------------------------------------------------------
// Decoder: logits[b,i,a] = sum_{l<=i} sum_f act[l,b,f] * WdecT[tri(i,l),a,f]
// grid 576, heavy layers first (LPT-style greedy balance).
// ---------------------------------------------------------------------------
__global__ __launch_bounds__(512, 2) void dec_gemm8(
    const unsigned short* __restrict__ act,    // (L,B,F)
    const unsigned short* __restrict__ wdecT,  // (NTRI,A,F)
    float* __restrict__ logits)                // (B,L,A)
{
  extern __shared__ __align__(16) char lds[];
  char* AS = lds;
  char* BS = lds + 65536;
  const int b = blockIdx.x;
  const int z = b / 48;            // 0..11, heavy first
  const int blk = b - z * 48;      // 0..47
  const int i = 11 - z;
  const int m0 = (blk & 15) * 256;
  const int n0 = (blk >> 4) * 256; // {0,256,512}
  const int triBase = i * (i + 1) / 2;
  const int KT = (i + 1) * 64;
  const int tid = threadIdx.x;
  const int w = tid >> 6, lane = tid & 63;
  const int wr = w >> 2, wc = w & 3;
  const int sg = (lane & 7) ^ (lane >> 3);
  const int srow = w * 8 + (lane >> 3);

  const char* gA0 = (const char*)act + ((size_t)(m0 + srow)) * (F_ * 2) + sg * 16;
  const char* gB0 = (const char*)wdecT +
      ((size_t)(triBase * A_ + n0 + srow)) * (F_ * 2) + sg * 16;

  f32x4 acc[8][4] = {};
  auto koffA = [](int kt) {
    return (uint32_t)(kt >> 6) * (uint32_t)(B_ * F_ * 2) +
           (uint32_t)(kt & 63) * 128u;
  };
  auto koffB = [](int kt) {
    return (uint32_t)(kt >> 6) * (uint32_t)(A_ * F_ * 2) +
           (uint32_t)(kt & 63) * 128u;
  };
  gemm_core64(KT, AS, BS, gA0, gB0, F_ * 2, F_ * 2, w, wr, wc, lane,
              koffA, koffB, acc);

  const int g = lane >> 4, fr = lane & 15;
#pragma unroll
  for (int mi = 0; mi < 8; ++mi) {
    const int growb = m0 + wr * 128 + mi * 16 + g * 4;
#pragma unroll
    for (int ni = 0; ni < 4; ++ni) {
      const int gcol = n0 + wc * 64 + ni * 16 + fr;
#pragma unroll
      for (int jj = 0; jj < 4; ++jj)
        logits[((size_t)(growb + jj) * L_ + i) * A_ + gcol] = acc[mi][ni][jj];
    }
  }
}

// ---------------------------------------------------------------------------
extern "C" void kernel_launch(void* const* d_in, const int* in_sizes, int n_in,
                              void* d_out, int out_size, void* d_ws,
                              size_t ws_size, hipStream_t stream) {
  (void)in_sizes; (void)n_in; (void)out_size; (void)ws_size;
  const float* x = (const float*)d_in[0];
  const float* mean = (const float*)d_in[1];
  const float* stdv = (const float*)d_in[2];
  const float* Wenc = (const float*)d_in[3];
  const float* theta = (const float*)d_in[4];
  const float* Wdec = (const float*)d_in[5];

  float* logits = (float*)d_out;
  float* enc = (float*)d_out + (size_t)B_ * L_ * A_;

  char* ws = (char*)d_ws;
  const size_t actBytes = (size_t)L_ * B_ * F_ * 2;      // 402.7 MB
  const size_t sxBytes = (size_t)L_ * B_ * A_ * 2;       // 75.5 MB
  unsigned short* act = (unsigned short*)ws;
  unsigned short* sx = (unsigned short*)(ws + actBytes);
  unsigned short* wencT = (unsigned short*)(ws + actBytes + sxBytes);
  // W_dec^T only needed after the encoder; alias it over sx/wencT.
  unsigned short* wdecT = (unsigned short*)(ws + actBytes);

  hipFuncSetAttribute((const void*)enc_gemm8,
                      hipFuncAttributeMaxDynamicSharedMemorySize, 131072);
  hipFuncSetAttribute((const void*)dec_gemm8,
                      hipFuncAttributeMaxDynamicSharedMemorySize, 131072);

  prep_sx<<<(B_ * L_ * A_ / 4 + 255) / 256, 256, 0, stream>>>(x, mean, stdv, sx);
  transpose_cvt64<<<dim3(F_ / 64, A_ / 64, L_), 256, 0, stream>>>(
      Wenc, wencT, A_, F_);
  enc_gemm8<<<3072, 512, 131072, stream>>>(sx, wencT, theta, enc, act);
  transpose_cvt64<<<dim3(A_ / 64, F_ / 64, NTRI), 256, 0, stream>>>(
      Wdec, wdecT, F_, A_);
  dec_gemm8<<<576, 512, 131072, stream>>>(act, wdecT, logits);
}